// Round 5
// baseline (719.280 us; speedup 1.0000x reference)
//
#include <hip/hip_runtime.h>
#include <stdint.h>

#define B_ 8
#define C_ 256
#define N_ 4096
#define M_ 4096
#define NT 64
#define MT 64
#define PP 72    // sP pitch (64 + 8 pad)
#define L2E 1.44269504f

typedef _Float16 f16x8 __attribute__((ext_vector_type(8)));
typedef _Float16 f16x4 __attribute__((ext_vector_type(4)));
typedef float f32x4 __attribute__((ext_vector_type(4)));

__device__ __forceinline__ void async16(const _Float16* g, _Float16* l) {
    __builtin_amdgcn_global_load_lds(
        (const __attribute__((address_space(1))) void*)g,
        (__attribute__((address_space(3))) void*)l, 16, 0, 0);
}

// fused pre-pass: blocks [0,512) transpose xs -> kt [B,M,C] fp16 (4 sub-tiles each);
//                 blocks [512,2560) convert ys -> vb [B,C,M] fp16 (16 elems/thread)
__global__ __launch_bounds__(256) void kPre(const float* __restrict__ xs,
                                            const float* __restrict__ ys,
                                            _Float16* __restrict__ kt,
                                            _Float16* __restrict__ vb) {
    int bx = blockIdx.x;
    int t = threadIdx.x;
    if (bx < 512) {
        __shared__ float tile[64][65];
        int b = bx >> 6, c0 = ((bx >> 4) & 3) * 64, ms = (bx & 15) * 256;
#pragma unroll
        for (int mi = 0; mi < 4; mi++) {
            int m0 = ms + mi * 64;
            if (mi) __syncthreads();
            int cl = t >> 4, m4 = (t & 15) * 4;
#pragma unroll
            for (int i = 0; i < 4; i++) {
                int c = c0 + cl + i * 16;
                const float4 v = *(const float4*)(xs + ((size_t)(b * C_ + c) * M_) + m0 + m4);
                tile[m4 + 0][cl + i * 16] = v.x;
                tile[m4 + 1][cl + i * 16] = v.y;
                tile[m4 + 2][cl + i * 16] = v.z;
                tile[m4 + 3][cl + i * 16] = v.w;
            }
            __syncthreads();
            int ml = t >> 4, c4 = (t & 15) * 4;
#pragma unroll
            for (int i = 0; i < 4; i++) {
                int m = m0 + ml + i * 16;
                f16x4 o;
                o[0] = (_Float16)tile[ml + i * 16][c4 + 0];
                o[1] = (_Float16)tile[ml + i * 16][c4 + 1];
                o[2] = (_Float16)tile[ml + i * 16][c4 + 2];
                o[3] = (_Float16)tile[ml + i * 16][c4 + 3];
                *(f16x4*)(kt + ((size_t)(b * M_ + m) * C_) + c0 + c4) = o;
            }
        }
    } else {
        size_t base = ((size_t)(bx - 512) * 256 + t) * 16;
#pragma unroll
        for (int j = 0; j < 2; j++) {
            float4 a = *(const float4*)(ys + base + j * 8);
            float4 c = *(const float4*)(ys + base + j * 8 + 4);
            f16x8 o;
            o[0] = (_Float16)a.x; o[1] = (_Float16)a.y;
            o[2] = (_Float16)a.z; o[3] = (_Float16)a.w;
            o[4] = (_Float16)c.x; o[5] = (_Float16)c.y;
            o[6] = (_Float16)c.z; o[7] = (_Float16)c.w;
            *(f16x8*)(vb + base + j * 8) = o;
        }
    }
}

// flash-attention: 512 threads (8 waves), one block per (batch, 64-query tile), 2 blocks/CU
// S split: wn=w&3 row strip (16 n), wm=w>>2 m-half (32 m). PV split: wave c-strip of 32.
__global__ __launch_bounds__(512, 4) void kAttn(const float* __restrict__ h,
                                                const _Float16* __restrict__ kt,
                                                const _Float16* __restrict__ vb,
                                                float* __restrict__ out) {
    __shared__ _Float16 sK[2][MT * 256];     // 64 KB; sK[1] holds Q in prologue
    __shared__ _Float16 sP[NT * PP];         // 9.2 KB
    __shared__ float sMaxP[2][NT];
    __shared__ float sLP[2][NT];
    __shared__ float sAlpha[NT];
    __shared__ int sFlag[2];

    const int t = threadIdx.x;
    const int w = t >> 6, lane = t & 63, quad = lane >> 4, l15 = lane & 15;
    const int wn = w & 3, wm = w >> 2;
    const int b = blockIdx.x >> 6;
    const int n0 = (blockIdx.x & 63) * NT;
    const int nb = wn * 16;   // softmax row strip
    const int cb = w * 32;    // PV channel strip

    const _Float16* srcKb = kt + (size_t)b * M_ * C_;
    const _Float16* srcVb = vb + (size_t)b * C_ * M_;

    if (t == 0) { sFlag[0] = 0; sFlag[1] = 0; }

    // ---- stage Q (transposed+swizzled) into sK[1] ----
    {
        int cl = t >> 4, n4 = (t & 15) * 4;
#pragma unroll
        for (int i = 0; i < 8; i++) {
            int c = i * 32 + cl;
            const float4 v = *(const float4*)(h + ((size_t)(b * C_ + c) * N_) + n0 + n4);
            float xv[4] = {v.x, v.y, v.z, v.w};
#pragma unroll
            for (int j = 0; j < 4; j++) {
                int row = n4 + j;
                sK[1][row * 256 + (((c >> 3) ^ (row & 31)) << 3) + (c & 7)] = (_Float16)xv[j];
            }
        }
    }
    __syncthreads();

    f16x8 qf[8];
    {
        int qrow = nb + l15;
#pragma unroll
        for (int ks = 0; ks < 8; ks++)
            qf[ks] = *(const f16x8*)(&sK[1][qrow * 256 + ((((ks << 2) + quad) ^ (qrow & 31)) << 3)]);
    }
    __syncthreads();   // all qf reads done before sK[1] can be overwritten by prefetch

    // issue K tile 0 into sK[0]: wave w covers rows [8w, 8w+8)
#pragma unroll
    for (int j = 0; j < 4; j++) {
        int row = w * 8 + j * 2 + (lane >> 5);
        int logi = (lane & 31) ^ (row & 31);
        async16(srcKb + (size_t)row * C_ + logi * 8, &sK[0][(w * 8 + j * 2) * 256]);
    }

    f32x4 o[2][4];
#pragma unroll
    for (int i = 0; i < 2; i++)
#pragma unroll
        for (int j = 0; j < 4; j++)
            o[i][j] = (f32x4){0.f, 0.f, 0.f, 0.f};

    float mst[4], lp[4];
#pragma unroll
    for (int r = 0; r < 4; r++) { mst[r] = -3.0e38f; lp[r] = 0.f; }

    for (int it = 0; it < M_ / MT; it++) {
        const int cur = it & 1;
        const int m0i = it * MT;
        // A: K[it] drained (vmcnt) + visible; sK[cur^1] & sP free
        __syncthreads();
        if (t == 0) sFlag[cur ^ 1] = 0;

        // V fragments: global->reg, wave-exclusive c-strip
        f16x8 vf[2][2];
#pragma unroll
        for (int ks = 0; ks < 2; ks++)
#pragma unroll
            for (int ct = 0; ct < 2; ct++) {
                int vrow = cb + ct * 16 + l15;
                vf[ks][ct] = *(const f16x8*)(srcVb + (size_t)vrow * M_ + m0i + ks * 32 + quad * 8);
            }

        // ---- S = Q·K^T : rows [nb,nb+16) x m-half [wm*32, wm*32+32) ----
        f32x4 s[2];
        s[0] = (f32x4){0.f, 0.f, 0.f, 0.f};
        s[1] = (f32x4){0.f, 0.f, 0.f, 0.f};
#pragma unroll
        for (int ks = 0; ks < 8; ks++) {
#pragma unroll
            for (int l = 0; l < 2; l++) {
                int krow = wm * 32 + l * 16 + l15;
                f16x8 bk = *(const f16x8*)(&sK[cur][krow * 256 + ((((ks << 2) + quad) ^ (krow & 31)) << 3)]);
                s[l] = __builtin_amdgcn_mfma_f32_16x16x32_f16(qf[ks], bk, s[l], 0, 0, 0);
            }
        }

        // ---- partial rowmax over this wave's m-half ----
#pragma unroll
        for (int r = 0; r < 4; r++) {
            float pm = fmaxf(s[0][r], s[1][r]);
#pragma unroll
            for (int off = 1; off < 16; off <<= 1)
                pm = fmaxf(pm, __shfl_xor(pm, off, 64));
            if (l15 == 0) sMaxP[wm][nb + quad * 4 + r] = pm;
        }
        __syncthreads();   // M: both halves' partial maxima visible

        // ---- merge max, exp, P-write, alpha ----
#pragma unroll
        for (int r = 0; r < 4; r++) {
            int row = nb + quad * 4 + r;
            float rowmax = fmaxf(sMaxP[0][row], sMaxP[1][row]);
            float al = 1.0f;
            if (rowmax > mst[r]) {
                al = exp2f((mst[r] - rowmax) * L2E);
                mst[r] = rowmax;
            }
            float psum = 0.f;
#pragma unroll
            for (int l = 0; l < 2; l++) {
                float p = exp2f((s[l][r] - mst[r]) * L2E);
                s[l][r] = p;
                psum += p;
            }
            lp[r] = lp[r] * al + psum;
            if (l15 == 0) {
                sAlpha[row] = al;   // both wm waves write same value
                if (al != 1.0f) atomicOr(&sFlag[cur], 1);
            }
#pragma unroll
            for (int l = 0; l < 2; l++)
                sP[row * PP + wm * 32 + l * 16 + l15] = (_Float16)s[l][r];
        }
        __syncthreads();   // B: sP + sAlpha + sFlag visible

        // issue K[it+1] here: vmcnt drain happens at next barrier A, after full PV
        if (it + 1 < M_ / MT) {
            const _Float16* srcK = srcKb + (size_t)(m0i + MT) * C_;
#pragma unroll
            for (int j = 0; j < 4; j++) {
                int row = w * 8 + j * 2 + (lane >> 5);
                int logi = (lane & 31) ^ (row & 31);
                async16(srcK + (size_t)row * C_ + logi * 8, &sK[cur ^ 1][(w * 8 + j * 2) * 256]);
            }
        }

        // ---- rescale O only if some row's max moved ----
        if (sFlag[cur]) {
            float av[4];
#pragma unroll
            for (int nt = 0; nt < 4; nt++) av[nt] = sAlpha[nt * 16 + l15];
#pragma unroll
            for (int ct = 0; ct < 2; ct++)
#pragma unroll
                for (int nt = 0; nt < 4; nt++) {
                    o[ct][nt][0] *= av[nt];
                    o[ct][nt][1] *= av[nt];
                    o[ct][nt][2] *= av[nt];
                    o[ct][nt][3] *= av[nt];
                }
        }

        // ---- O += V·P^T ----
#pragma unroll
        for (int ks = 0; ks < 2; ks++) {
#pragma unroll
            for (int nt = 0; nt < 4; nt++) {
                f16x8 bp = *(const f16x8*)(sP + (nt * 16 + l15) * PP + ks * 32 + quad * 8);
#pragma unroll
                for (int ct = 0; ct < 2; ct++)
                    o[ct][nt] = __builtin_amdgcn_mfma_f32_16x16x32_f16(vf[ks][ct], bp, o[ct][nt], 0, 0, 0);
            }
        }
    }

    // ---- epilogue: reduce lp over 16-lane group, then across wm halves ----
#pragma unroll
    for (int r = 0; r < 4; r++) {
#pragma unroll
        for (int off = 1; off < 16; off <<= 1)
            lp[r] += __shfl_xor(lp[r], off, 64);
        if (l15 == 0) sLP[wm][nb + quad * 4 + r] = lp[r];
    }
    __syncthreads();
    float linv[4];
#pragma unroll
    for (int nt = 0; nt < 4; nt++) {
        int n = nt * 16 + l15;
        linv[nt] = 1.0f / (sLP[0][n] + sLP[1][n]);
    }
#pragma unroll
    for (int ct = 0; ct < 2; ct++)
#pragma unroll
        for (int nt = 0; nt < 4; nt++)
#pragma unroll
            for (int r = 0; r < 4; r++) {
                int c = cb + ct * 16 + quad * 4 + r;
                out[((size_t)(b * C_ + c)) * N_ + n0 + nt * 16 + l15] = o[ct][nt][r] * linv[nt];
            }
}

extern "C" void kernel_launch(void* const* d_in, const int* in_sizes, int n_in,
                              void* d_out, int out_size, void* d_ws, size_t ws_size,
                              hipStream_t stream) {
    const float* h  = (const float*)d_in[0];
    const float* xs = (const float*)d_in[1];
    const float* ys = (const float*)d_in[2];
    float* out = (float*)d_out;

    _Float16* kt  = (_Float16*)d_ws;                    // [B,M,C] fp16: 16 MB
    _Float16* vbb = kt + (size_t)B_ * M_ * C_;          // [B,C,M] fp16: 16 MB

    kPre<<<dim3(512 + 2048), 256, 0, stream>>>(xs, ys, kt, vbb);
    kAttn<<<dim3(B_ * (N_ / NT)), 512, 0, stream>>>(h, kt, vbb, out);
}